// Round 10
// baseline (276.230 us; speedup 1.0000x reference)
//
#include <hip/hip_runtime.h>

typedef _Float16 half8 __attribute__((ext_vector_type(8)));
typedef _Float16 half4 __attribute__((ext_vector_type(4)));
typedef float f32x4 __attribute__((ext_vector_type(4)));

#define MFMA16(a, b, c) __builtin_amdgcn_mfma_f32_16x16x32_f16((a), (b), (c), 0, 0, 0)
#define MFMA16K16(a, b, c) __builtin_amdgcn_mfma_f32_16x16x16f16((a), (b), (c), 0, 0, 0)
#define EXP2F(x) __builtin_amdgcn_exp2f(x)

// Q is pre-scaled by softmax_scale * log2(e) in the qkv epilogue.
#define QSCALE 0.18033688f  // 0.125 * log2(e)

// ---------------- cast kernels ----------------

__global__ __launch_bounds__(256) void cast_f32_f16(const float* __restrict__ x,
                                                    _Float16* __restrict__ y, int n) {
    for (int i = (blockIdx.x * 256 + threadIdx.x) * 4; i < n; i += gridDim.x * 256 * 4) {
        float4 v = *(const float4*)(x + i);
        half4 h = {(_Float16)v.x, (_Float16)v.y, (_Float16)v.z, (_Float16)v.w};
        *(half4*)(y + i) = h;
    }
}

// W [K][N] fp32 -> Wt [N][K] fp16
__global__ __launch_bounds__(256) void transpose_cast(const float* __restrict__ W,
                                                      _Float16* __restrict__ Wt,
                                                      int K, int N) {
    __shared__ _Float16 tile[32][33];
    int n0 = blockIdx.x * 32, k0 = blockIdx.y * 32;
    int c = threadIdx.x & 31, r4 = threadIdx.x >> 5;
    for (int i = 0; i < 4; i++) {
        int r = r4 + i * 8;
        tile[r][c] = (_Float16)W[(k0 + r) * N + n0 + c];
    }
    __syncthreads();
    for (int i = 0; i < 4; i++) {
        int r = r4 + i * 8;  // n within tile
        Wt[(n0 + r) * K + k0 + c] = tile[c][r];
    }
}

// ---------------- QKV GEMM: barrier-free direct-to-register ----------------
// R7-R9 evidence: MfmaUtil ~16% = MFMA pipe work equals the 10 us floor but
// spread over 61 us; 2-barrier LDS K-loop is latency/phase-lock-bound (the
// documented m97-structure plateau at small K). Fix = AITER-style loop:
// per-wave fragments loaded straight global->VGPR, register ping-pong at
// K=32 granularity, ZERO barriers -> waves free-run, vmcnt never drains.
// LDS reuse lost (2x) is covered by L1/L2; XCD remap keeps A-strip resident.

__global__ __launch_bounds__(256) void gemm_qkv(const _Float16* __restrict__ A,
                                                const _Float16* __restrict__ Bt,
                                                const float* __restrict__ bias,
                                                _Float16* __restrict__ Qo,
                                                _Float16* __restrict__ Ko,
                                                _Float16* __restrict__ Vto) {
    const int tid = threadIdx.x;
    // XCD-affinity remap (grid 24 x 32; lin%8 = XCD round-robin)
    const int lin = blockIdx.x + 24 * blockIdx.y;
    const int xcd = lin & 7, slot = lin >> 3;
    const int n0 = (slot >> 2) * 128;
    const int m0 = (xcd * 4 + (slot & 3)) * 128;
    const int wave = tid >> 6, lane = tid & 63;
    const int quad = lane >> 4, l15 = lane & 15;
    const int wrow = (wave >> 1) * 64, wcol = (wave & 1) * 64;

    // per-lane fixed row bases (k advances via offset)
    const _Float16* Ab[4];
    const _Float16* Bb[4];
    for (int mi = 0; mi < 4; mi++)
        Ab[mi] = A + (size_t)(m0 + wrow + mi * 16 + l15) * 1024 + quad * 8;
    for (int ni = 0; ni < 4; ni++)
        Bb[ni] = Bt + (size_t)(n0 + wcol + ni * 16 + l15) * 1024 + quad * 8;

    f32x4 acc[4][4] = {};
    half8 a0[4], b0[4], a1[4], b1[4];
    for (int i = 0; i < 4; i++) { a0[i] = *(const half8*)(Ab[i]); b0[i] = *(const half8*)(Bb[i]); }

#pragma unroll 4
    for (int k = 0; k < 1024; k += 64) {
        // prefetch k+32 while computing on k
        if (k + 32 < 1024)
            for (int i = 0; i < 4; i++) {
                a1[i] = *(const half8*)(Ab[i] + k + 32);
                b1[i] = *(const half8*)(Bb[i] + k + 32);
            }
        for (int mi = 0; mi < 4; mi++)
            for (int ni = 0; ni < 4; ni++)
                acc[mi][ni] = MFMA16(a0[mi], b0[ni], acc[mi][ni]);
        if (k + 64 < 1024)
            for (int i = 0; i < 4; i++) {
                a0[i] = *(const half8*)(Ab[i] + k + 64);
                b0[i] = *(const half8*)(Bb[i] + k + 64);
            }
        for (int mi = 0; mi < 4; mi++)
            for (int ni = 0; ni < 4; ni++)
                acc[mi][ni] = MFMA16(a1[mi], b1[ni], acc[mi][ni]);
    }

    // epilogue: scatter to Q [BH][T][64] (pre-scaled), K [BH][T][64], Vt [BH][64][T]
    for (int mi = 0; mi < 4; mi++)
        for (int ni = 0; ni < 4; ni++) {
            int gn = n0 + wcol + ni * 16 + l15;
            int which = gn >> 10, rem = gn & 1023;
            int h = rem >> 6, dh = rem & 63;
            float bv = bias[gn];
            for (int r = 0; r < 4; r++) {
                int gm = m0 + wrow + mi * 16 + quad * 4 + r;
                int b = gm >> 11, t = gm & 2047;
                int bh = b * 16 + h;
                float v = acc[mi][ni][r] + bv;
                if (which == 0)      Qo[(bh * 2048 + t) * 64 + dh] = (_Float16)(v * QSCALE);
                else if (which == 1) Ko[(bh * 2048 + t) * 64 + dh] = (_Float16)v;
                else                 Vto[(bh * 64 + dh) * 2048 + t] = (_Float16)v;
            }
        }
}

// ---------------- flash attention, transpose-S (exact R7 config, best attn) ----------------
// grid (32 bh, 16 qt): 128 q per block, 32 q per wave (two 16-q groups).
// R9 lesson: BK=256 dropped occupancy to 1 block/CU (m132 repeat) - reverted.
// Ks[128][64] XOR-swizzled; Vs[64][132] stride 66 dw == 2 mod 32 (conflict-free).

__global__ __launch_bounds__(256) void attn_kernel(const _Float16* __restrict__ Qg,
                                                   const _Float16* __restrict__ Kg,
                                                   const _Float16* __restrict__ Vtg,
                                                   _Float16* __restrict__ AO) {
    __shared__ _Float16 Ks[128][64];
    __shared__ _Float16 Vs[64][132];

    const int tid = threadIdx.x;
    const int bh = blockIdx.x;
    const int q0 = blockIdx.y * 128;
    const int b = bh >> 4, h = bh & 15;
    const int wave = tid >> 6, lane = tid & 63;
    const int quad = lane >> 4, l15 = lane & 15;
    const int akey = l15 & 7;

    half8 qf[2][2];
    for (int g = 0; g < 2; g++) {
        const int qrow = q0 + wave * 32 + g * 16 + l15;
        for (int kk = 0; kk < 2; kk++)
            qf[g][kk] = *(const half8*)(&Qg[(bh * 2048 + qrow) * 64 + kk * 32 + quad * 8]);
    }

    const int srow = tid >> 3;
    const int sgcol = (tid & 7) * 8;
    const int sscol = (((tid & 7) ^ (srow & 7))) * 8;
    const int vrow = tid >> 4;
    const int vgcol = (tid & 15) * 8;

    const _Float16* Kbase = Kg + (size_t)bh * 2048 * 64;
    const _Float16* Vbase = Vtg + (size_t)bh * 64 * 2048;

    half8 kreg[4], vreg[4];
    for (int i = 0; i < 4; i++)
        kreg[i] = *(const half8*)(Kbase + (srow + i * 32) * 64 + sgcol);
    for (int i = 0; i < 4; i++)
        vreg[i] = *(const half8*)(Vbase + (vrow + i * 16) * 2048 + vgcol);

    float lsum[2] = {0.f, 0.f};
    f32x4 oacc[2][4] = {};

    for (int kt = 0; kt < 16; kt++) {
        __syncthreads();
        for (int i = 0; i < 4; i++)
            *(half8*)(&Ks[srow + i * 32][sscol]) = kreg[i];
        for (int i = 0; i < 4; i++)
            *(half8*)(&Vs[vrow + i * 16][vgcol]) = vreg[i];
        __syncthreads();
        if (kt < 15) {
            const int kb = (kt + 1) * 128;
            for (int i = 0; i < 4; i++)
                kreg[i] = *(const half8*)(Kbase + (kb + srow + i * 32) * 64 + sgcol);
            for (int i = 0; i < 4; i++)
                vreg[i] = *(const half8*)(Vbase + (vrow + i * 16) * 2048 + kb + vgcol);
        }

#pragma unroll
        for (int ni = 0; ni < 8; ni++) {
            half8 ka = *(const half8*)(&Ks[ni * 16 + l15][(quad ^ akey) * 8]);
            half8 kb2 = *(const half8*)(&Ks[ni * 16 + l15][((quad + 4) ^ akey) * 8]);
            f32x4 s0 = {}, s1 = {};
            s0 = MFMA16(ka, qf[0][0], s0);
            s0 = MFMA16(kb2, qf[0][1], s0);
            s1 = MFMA16(ka, qf[1][0], s1);
            s1 = MFMA16(kb2, qf[1][1], s1);
            half4 bP0, bP1;
            float e;
            float a0 = 0.f, a1 = 0.f;
            e = EXP2F(s0[0]); a0 += e; bP0[0] = (_Float16)e;
            e = EXP2F(s0[1]); a0 += e; bP0[1] = (_Float16)e;
            e = EXP2F(s0[2]); a0 += e; bP0[2] = (_Float16)e;
            e = EXP2F(s0[3]); a0 += e; bP0[3] = (_Float16)e;
            e = EXP2F(s1[0]); a1 += e; bP1[0] = (_Float16)e;
            e = EXP2F(s1[1]); a1 += e; bP1[1] = (_Float16)e;
            e = EXP2F(s1[2]); a1 += e; bP1[2] = (_Float16)e;
            e = EXP2F(s1[3]); a1 += e; bP1[3] = (_Float16)e;
            lsum[0] += a0; lsum[1] += a1;
#pragma unroll
            for (int di = 0; di < 4; di++) {
                half4 av = *(const half4*)(&Vs[di * 16 + l15][ni * 16 + quad * 4]);
                oacc[0][di] = MFMA16K16(av, bP0, oacc[0][di]);
                oacc[1][di] = MFMA16K16(av, bP1, oacc[1][di]);
            }
        }
    }

    for (int g = 0; g < 2; g++) {
        float s = lsum[g];
        s += __shfl_xor(s, 16, 64);
        s += __shfl_xor(s, 32, 64);
        float inv = 1.f / s;
        const int qrow = q0 + wave * 32 + g * 16 + l15;
        for (int di = 0; di < 4; di++) {
            half4 hv;
            hv[0] = (_Float16)(oacc[g][di][0] * inv);
            hv[1] = (_Float16)(oacc[g][di][1] * inv);
            hv[2] = (_Float16)(oacc[g][di][2] * inv);
            hv[3] = (_Float16)(oacc[g][di][3] * inv);
            *(half4*)(&AO[(size_t)(b * 2048 + qrow) * 1024 + h * 64 + di * 16 + quad * 4]) = hv;
        }
    }
}

// ---------------- proj GEMM: barrier-free direct-to-register ----------------
// 64x128 tiles, grid (8,64) + XCD remap. Wave w: 64 m x 32 n (acc 4x2).
// A-frags shared by all 4 waves -> L1 covers the redundancy.

__global__ __launch_bounds__(256) void gemm_proj(const _Float16* __restrict__ A,
                                                 const _Float16* __restrict__ Bt,
                                                 const float* __restrict__ bias,
                                                 float* __restrict__ out) {
    const int tid = threadIdx.x;
    const int lin = blockIdx.x + 8 * blockIdx.y;
    const int xcd = lin & 7, slot = lin >> 3;     // slot 0..63
    const int n0 = (slot >> 3) * 128;
    const int m0 = (xcd * 8 + (slot & 7)) * 64;
    const int wave = tid >> 6, lane = tid & 63;
    const int quad = lane >> 4, l15 = lane & 15;

    const _Float16* Ab[4];
    const _Float16* Bb[2];
    for (int mi = 0; mi < 4; mi++)
        Ab[mi] = A + (size_t)(m0 + mi * 16 + l15) * 1024 + quad * 8;
    for (int ni = 0; ni < 2; ni++)
        Bb[ni] = Bt + (size_t)(n0 + wave * 32 + ni * 16 + l15) * 1024 + quad * 8;

    f32x4 acc[4][2] = {};
    half8 a0[4], b0[2], a1[4], b1[2];
    for (int i = 0; i < 4; i++) a0[i] = *(const half8*)(Ab[i]);
    for (int i = 0; i < 2; i++) b0[i] = *(const half8*)(Bb[i]);

#pragma unroll 4
    for (int k = 0; k < 1024; k += 64) {
        if (k + 32 < 1024) {
            for (int i = 0; i < 4; i++) a1[i] = *(const half8*)(Ab[i] + k + 32);
            for (int i = 0; i < 2; i++) b1[i] = *(const half8*)(Bb[i] + k + 32);
        }
        for (int mi = 0; mi < 4; mi++)
            for (int ni = 0; ni < 2; ni++)
                acc[mi][ni] = MFMA16(a0[mi], b0[ni], acc[mi][ni]);
        if (k + 64 < 1024) {
            for (int i = 0; i < 4; i++) a0[i] = *(const half8*)(Ab[i] + k + 64);
            for (int i = 0; i < 2; i++) b0[i] = *(const half8*)(Bb[i] + k + 64);
        }
        for (int mi = 0; mi < 4; mi++)
            for (int ni = 0; ni < 2; ni++)
                acc[mi][ni] = MFMA16(a1[mi], b1[ni], acc[mi][ni]);
    }

    for (int mi = 0; mi < 4; mi++)
        for (int ni = 0; ni < 2; ni++) {
            int gn = n0 + wave * 32 + ni * 16 + l15;
            float bv = bias[gn];
            for (int r = 0; r < 4; r++) {
                int gm = m0 + mi * 16 + quad * 4 + r;
                out[(size_t)gm * 1024 + gn] = acc[mi][ni][r] + bv;
            }
        }
}

// ---------------- launch ----------------

extern "C" void kernel_launch(void* const* d_in, const int* in_sizes, int n_in,
                              void* d_out, int out_size, void* d_ws, size_t ws_size,
                              hipStream_t stream) {
    const float* x     = (const float*)d_in[0];
    const float* Wqkv  = (const float*)d_in[1];
    const float* bqkv  = (const float*)d_in[2];
    const float* Wproj = (const float*)d_in[3];
    const float* bproj = (const float*)d_in[4];
    float* out = (float*)d_out;

    char* ws = (char*)d_ws;
    const size_t MB = 1024 * 1024;
    _Float16* Xh  = (_Float16*)(ws + 0 * MB);   // [4096][1024]   8 MB
    _Float16* Wqt = (_Float16*)(ws + 8 * MB);   // [3072][1024]   6 MB
    _Float16* Wpt = (_Float16*)(ws + 14 * MB);  // [1024][1024]   2 MB
    _Float16* Qg  = (_Float16*)(ws + 16 * MB);  // [32][2048][64] 8 MB (pre-scaled)
    _Float16* Kg  = (_Float16*)(ws + 24 * MB);  // [32][2048][64] 8 MB
    _Float16* Vtg = (_Float16*)(ws + 32 * MB);  // [32][64][2048] 8 MB
    _Float16* AO  = (_Float16*)(ws + 40 * MB);  // [4096][1024]   8 MB

    cast_f32_f16<<<1024, 256, 0, stream>>>(x, Xh, 4096 * 1024);
    transpose_cast<<<dim3(96, 32), 256, 0, stream>>>(Wqkv, Wqt, 1024, 3072);
    transpose_cast<<<dim3(32, 32), 256, 0, stream>>>(Wproj, Wpt, 1024, 1024);
    gemm_qkv<<<dim3(24, 32), 256, 0, stream>>>(Xh, Wqt, bqkv, Qg, Kg, Vtg);
    attn_kernel<<<dim3(32, 16), 256, 0, stream>>>(Qg, Kg, Vtg, AO);
    gemm_proj<<<dim3(8, 64), 256, 0, stream>>>(AO, Wpt, bproj, out);
}

// Round 11
// 195.442 us; speedup vs baseline: 1.4134x; 1.4134x over previous
//
#include <hip/hip_runtime.h>

typedef _Float16 half8 __attribute__((ext_vector_type(8)));
typedef _Float16 half4 __attribute__((ext_vector_type(4)));
typedef float f32x4 __attribute__((ext_vector_type(4)));

#define MFMA16(a, b, c) __builtin_amdgcn_mfma_f32_16x16x32_f16((a), (b), (c), 0, 0, 0)
#define MFMA16K16(a, b, c) __builtin_amdgcn_mfma_f32_16x16x16f16((a), (b), (c), 0, 0, 0)
#define EXP2F(x) __builtin_amdgcn_exp2f(x)

#define GLOBAL_LOAD_LDS16(gptr, lptr)                                        \
    __builtin_amdgcn_global_load_lds(                                        \
        (const __attribute__((address_space(1))) void*)(gptr),               \
        (__attribute__((address_space(3))) void*)(lptr), 16, 0, 0)

// Q is pre-scaled by softmax_scale * log2(e) in the qkv epilogue.
#define QSCALE 0.18033688f  // 0.125 * log2(e)

// ---------------- fused prep: cast x + transpose-cast both weights ----------------
// One launch instead of three: removes 2 launch gaps; the three memory-bound
// phases pipeline across CUs.
// blocks [0,4096): cast x (1024 elems/block)
// blocks [4096,7168): transpose Wqkv tile (96 x 32 tiles)
// blocks [7168,8192): transpose Wproj tile (32 x 32 tiles)

__global__ __launch_bounds__(256) void prep_kernel(const float* __restrict__ x,
                                                   const float* __restrict__ Wqkv,
                                                   const float* __restrict__ Wproj,
                                                   _Float16* __restrict__ Xh,
                                                   _Float16* __restrict__ Wqt,
                                                   _Float16* __restrict__ Wpt) {
    const int bid = blockIdx.x;
    const int tid = threadIdx.x;
    if (bid < 4096) {
        int i = bid * 1024 + tid * 4;
        float4 v = *(const float4*)(x + i);
        half4 h = {(_Float16)v.x, (_Float16)v.y, (_Float16)v.z, (_Float16)v.w};
        *(half4*)(Xh + i) = h;
        return;
    }
    __shared__ _Float16 tile[32][33];
    const float* W;
    _Float16* Wt;
    int n0, k0, N;
    if (bid < 7168) {
        int t = bid - 4096;
        W = Wqkv; Wt = Wqt; N = 3072;
        n0 = (t % 96) * 32; k0 = (t / 96) * 32;
    } else {
        int t = bid - 7168;
        W = Wproj; Wt = Wpt; N = 1024;
        n0 = (t & 31) * 32; k0 = (t >> 5) * 32;
    }
    int c = tid & 31, r4 = tid >> 5;
    for (int i = 0; i < 4; i++) {
        int r = r4 + i * 8;
        tile[r][c] = (_Float16)W[(k0 + r) * N + n0 + c];
    }
    __syncthreads();
    for (int i = 0; i < 4; i++) {
        int r = r4 + i * 8;  // n within tile
        Wt[(n0 + r) * 1024 + k0 + c] = tile[c][r];
    }
}

// ---------------- QKV GEMM: C[4096,3072] = Xh @ Wqkv + b, scatter to Q/K/Vt ----------------
// R9 structure (best measured): single-buffer LDS + GLL width-16 staging,
// XOR swizzle (0 conflicts), XCD-affinity remap (per-XCD A-strip L2-resident).

__global__ __launch_bounds__(256) void gemm_qkv(const _Float16* __restrict__ A,
                                                const _Float16* __restrict__ Bt,
                                                const float* __restrict__ bias,
                                                _Float16* __restrict__ Qo,
                                                _Float16* __restrict__ Ko,
                                                _Float16* __restrict__ Vto) {
    __shared__ _Float16 As[128][64];
    __shared__ _Float16 Bs[128][64];
    const int tid = threadIdx.x;
    const int lin = blockIdx.x + 24 * blockIdx.y;
    const int xcd = lin & 7, slot = lin >> 3;     // slot 0..95
    const int n0 = (slot >> 2) * 128;             // 0..23
    const int m0 = (xcd * 4 + (slot & 3)) * 128;  // 0..31
    const int wave = tid >> 6, lane = tid & 63;
    const int quad = lane >> 4, l15 = lane & 15;
    const int sw = l15 & 7;
    const int wrow = (wave >> 1) * 64, wcol = (wave & 1) * 64;
    const int ldrow = wave * 32 + (lane >> 3);
    const int ldslot = (lane & 7) * 8;
    const int gcol = (((lane & 7) ^ (ldrow & 7))) * 8;

    f32x4 acc[4][4] = {};
    for (int k0 = 0; k0 < 1024; k0 += 64) {
        __syncthreads();
        for (int i = 0; i < 4; i++) {
            int r = ldrow + i * 8;
            GLOBAL_LOAD_LDS16(&A[(size_t)(m0 + r) * 1024 + k0 + gcol], &As[r][ldslot]);
            GLOBAL_LOAD_LDS16(&Bt[(size_t)(n0 + r) * 1024 + k0 + gcol], &Bs[r][ldslot]);
        }
        __syncthreads();
        for (int kk = 0; kk < 64; kk += 32) {
            const int rcol = (((kk >> 3) + quad) ^ sw) * 8;
            half8 af[4], bf[4];
            for (int mi = 0; mi < 4; mi++)
                af[mi] = *(const half8*)(&As[wrow + mi * 16 + l15][rcol]);
            for (int ni = 0; ni < 4; ni++)
                bf[ni] = *(const half8*)(&Bs[wcol + ni * 16 + l15][rcol]);
            for (int mi = 0; mi < 4; mi++)
                for (int ni = 0; ni < 4; ni++)
                    acc[mi][ni] = MFMA16(af[mi], bf[ni], acc[mi][ni]);
        }
    }
    for (int mi = 0; mi < 4; mi++)
        for (int ni = 0; ni < 4; ni++) {
            int gn = n0 + wcol + ni * 16 + l15;
            int which = gn >> 10, rem = gn & 1023;
            int h = rem >> 6, dh = rem & 63;
            float bv = bias[gn];
            for (int r = 0; r < 4; r++) {
                int gm = m0 + wrow + mi * 16 + quad * 4 + r;
                int b = gm >> 11, t = gm & 2047;
                int bh = b * 16 + h;
                float v = acc[mi][ni][r] + bv;
                if (which == 0)      Qo[(bh * 2048 + t) * 64 + dh] = (_Float16)(v * QSCALE);
                else if (which == 1) Ko[(bh * 2048 + t) * 64 + dh] = (_Float16)v;
                else                 Vto[(bh * 64 + dh) * 2048 + t] = (_Float16)v;
            }
        }
}

// ---------------- flash attention, transpose-S (best: R7 config) ----------------
// grid (32 bh, 16 qt): 128 q per block, 32 q per wave (two 16-q groups).
// Ks[128][64] XOR-swizzled; Vs[64][132] stride 66 dw == 2 mod 32 (conflict-free).
// 32.7 KB LDS. bh on x -> per-XCD K/V 2 MB L2-resident.

__global__ __launch_bounds__(256) void attn_kernel(const _Float16* __restrict__ Qg,
                                                   const _Float16* __restrict__ Kg,
                                                   const _Float16* __restrict__ Vtg,
                                                   _Float16* __restrict__ AO) {
    __shared__ _Float16 Ks[128][64];
    __shared__ _Float16 Vs[64][132];

    const int tid = threadIdx.x;
    const int bh = blockIdx.x;
    const int q0 = blockIdx.y * 128;
    const int b = bh >> 4, h = bh & 15;
    const int wave = tid >> 6, lane = tid & 63;
    const int quad = lane >> 4, l15 = lane & 15;
    const int akey = l15 & 7;

    half8 qf[2][2];
    for (int g = 0; g < 2; g++) {
        const int qrow = q0 + wave * 32 + g * 16 + l15;
        for (int kk = 0; kk < 2; kk++)
            qf[g][kk] = *(const half8*)(&Qg[(bh * 2048 + qrow) * 64 + kk * 32 + quad * 8]);
    }

    const int srow = tid >> 3;
    const int sgcol = (tid & 7) * 8;
    const int sscol = (((tid & 7) ^ (srow & 7))) * 8;
    const int vrow = tid >> 4;
    const int vgcol = (tid & 15) * 8;

    const _Float16* Kbase = Kg + (size_t)bh * 2048 * 64;
    const _Float16* Vbase = Vtg + (size_t)bh * 64 * 2048;

    half8 kreg[4], vreg[4];
    for (int i = 0; i < 4; i++)
        kreg[i] = *(const half8*)(Kbase + (srow + i * 32) * 64 + sgcol);
    for (int i = 0; i < 4; i++)
        vreg[i] = *(const half8*)(Vbase + (vrow + i * 16) * 2048 + vgcol);

    float lsum[2] = {0.f, 0.f};
    f32x4 oacc[2][4] = {};

    for (int kt = 0; kt < 16; kt++) {
        __syncthreads();
        for (int i = 0; i < 4; i++)
            *(half8*)(&Ks[srow + i * 32][sscol]) = kreg[i];
        for (int i = 0; i < 4; i++)
            *(half8*)(&Vs[vrow + i * 16][vgcol]) = vreg[i];
        __syncthreads();
        if (kt < 15) {
            const int kb = (kt + 1) * 128;
            for (int i = 0; i < 4; i++)
                kreg[i] = *(const half8*)(Kbase + (kb + srow + i * 32) * 64 + sgcol);
            for (int i = 0; i < 4; i++)
                vreg[i] = *(const half8*)(Vbase + (vrow + i * 16) * 2048 + kb + vgcol);
        }

#pragma unroll
        for (int ni = 0; ni < 8; ni++) {
            half8 ka = *(const half8*)(&Ks[ni * 16 + l15][(quad ^ akey) * 8]);
            half8 kb2 = *(const half8*)(&Ks[ni * 16 + l15][((quad + 4) ^ akey) * 8]);
            f32x4 s0 = {}, s1 = {};
            s0 = MFMA16(ka, qf[0][0], s0);
            s0 = MFMA16(kb2, qf[0][1], s0);
            s1 = MFMA16(ka, qf[1][0], s1);
            s1 = MFMA16(kb2, qf[1][1], s1);
            half4 bP0, bP1;
            float e;
            float a0 = 0.f, a1 = 0.f;
            e = EXP2F(s0[0]); a0 += e; bP0[0] = (_Float16)e;
            e = EXP2F(s0[1]); a0 += e; bP0[1] = (_Float16)e;
            e = EXP2F(s0[2]); a0 += e; bP0[2] = (_Float16)e;
            e = EXP2F(s0[3]); a0 += e; bP0[3] = (_Float16)e;
            e = EXP2F(s1[0]); a1 += e; bP1[0] = (_Float16)e;
            e = EXP2F(s1[1]); a1 += e; bP1[1] = (_Float16)e;
            e = EXP2F(s1[2]); a1 += e; bP1[2] = (_Float16)e;
            e = EXP2F(s1[3]); a1 += e; bP1[3] = (_Float16)e;
            lsum[0] += a0; lsum[1] += a1;
#pragma unroll
            for (int di = 0; di < 4; di++) {
                half4 av = *(const half4*)(&Vs[di * 16 + l15][ni * 16 + quad * 4]);
                oacc[0][di] = MFMA16K16(av, bP0, oacc[0][di]);
                oacc[1][di] = MFMA16K16(av, bP1, oacc[1][di]);
            }
        }
    }

    for (int g = 0; g < 2; g++) {
        float s = lsum[g];
        s += __shfl_xor(s, 16, 64);
        s += __shfl_xor(s, 32, 64);
        float inv = 1.f / s;
        const int qrow = q0 + wave * 32 + g * 16 + l15;
        for (int di = 0; di < 4; di++) {
            half4 hv;
            hv[0] = (_Float16)(oacc[g][di][0] * inv);
            hv[1] = (_Float16)(oacc[g][di][1] * inv);
            hv[2] = (_Float16)(oacc[g][di][2] * inv);
            hv[3] = (_Float16)(oacc[g][di][3] * inv);
            *(half4*)(&AO[(size_t)(b * 2048 + qrow) * 1024 + h * 64 + di * 16 + quad * 4]) = hv;
        }
    }
}

// ---------------- proj GEMM: out[4096,1024] = AO @ Wp + bp (fp32 out) ----------------
// R9 structure: 64x128 tile, GLL staging, XCD remap (AO-strip 1MB + Wpt 2MB
// per XCD, both L2-resident).

__global__ __launch_bounds__(256) void gemm_proj(const _Float16* __restrict__ A,
                                                 const _Float16* __restrict__ Bt,
                                                 const float* __restrict__ bias,
                                                 float* __restrict__ out) {
    __shared__ _Float16 As[64][64];    //  8 KB
    __shared__ _Float16 Bs[128][64];   // 16 KB
    const int tid = threadIdx.x;
    const int lin = blockIdx.x + 8 * blockIdx.y;
    const int xcd = lin & 7, slot = lin >> 3;     // slot 0..63
    const int n0 = (slot >> 3) * 128;
    const int m0 = (xcd * 8 + (slot & 7)) * 64;
    const int wave = tid >> 6, lane = tid & 63;
    const int quad = lane >> 4, l15 = lane & 15;
    const int sw = l15 & 7;
    const int ldrowA = wave * 16 + (lane >> 3);
    const int ldrowB = wave * 32 + (lane >> 3);
    const int ldslot = (lane & 7) * 8;
    const int gcolA = (((lane & 7) ^ (ldrowA & 7))) * 8;
    const int gcolB = (((lane & 7) ^ (ldrowB & 7))) * 8;

    f32x4 acc[4][2] = {};
    for (int k0 = 0; k0 < 1024; k0 += 64) {
        __syncthreads();
        for (int i = 0; i < 2; i++) {
            int r = ldrowA + i * 8;
            GLOBAL_LOAD_LDS16(&A[(size_t)(m0 + r) * 1024 + k0 + gcolA], &As[r][ldslot]);
        }
        for (int i = 0; i < 4; i++) {
            int r = ldrowB + i * 8;
            GLOBAL_LOAD_LDS16(&Bt[(size_t)(n0 + r) * 1024 + k0 + gcolB], &Bs[r][ldslot]);
        }
        __syncthreads();
        for (int kk = 0; kk < 64; kk += 32) {
            const int rcol = (((kk >> 3) + quad) ^ sw) * 8;
            half8 af[4], bf[2];
            for (int mi = 0; mi < 4; mi++)
                af[mi] = *(const half8*)(&As[mi * 16 + l15][rcol]);
            for (int ni = 0; ni < 2; ni++)
                bf[ni] = *(const half8*)(&Bs[wave * 32 + ni * 16 + l15][rcol]);
            for (int mi = 0; mi < 4; mi++)
                for (int ni = 0; ni < 2; ni++)
                    acc[mi][ni] = MFMA16(af[mi], bf[ni], acc[mi][ni]);
        }
    }
    for (int mi = 0; mi < 4; mi++)
        for (int ni = 0; ni < 2; ni++) {
            int gn = n0 + wave * 32 + ni * 16 + l15;
            float bv = bias[gn];
            for (int r = 0; r < 4; r++) {
                int gm = m0 + mi * 16 + quad * 4 + r;
                out[(size_t)gm * 1024 + gn] = acc[mi][ni][r] + bv;
            }
        }
}

// ---------------- launch ----------------

extern "C" void kernel_launch(void* const* d_in, const int* in_sizes, int n_in,
                              void* d_out, int out_size, void* d_ws, size_t ws_size,
                              hipStream_t stream) {
    const float* x     = (const float*)d_in[0];
    const float* Wqkv  = (const float*)d_in[1];
    const float* bqkv  = (const float*)d_in[2];
    const float* Wproj = (const float*)d_in[3];
    const float* bproj = (const float*)d_in[4];
    float* out = (float*)d_out;

    char* ws = (char*)d_ws;
    const size_t MB = 1024 * 1024;
    _Float16* Xh  = (_Float16*)(ws + 0 * MB);   // [4096][1024]   8 MB
    _Float16* Wqt = (_Float16*)(ws + 8 * MB);   // [3072][1024]   6 MB
    _Float16* Wpt = (_Float16*)(ws + 14 * MB);  // [1024][1024]   2 MB
    _Float16* Qg  = (_Float16*)(ws + 16 * MB);  // [32][2048][64] 8 MB (pre-scaled)
    _Float16* Kg  = (_Float16*)(ws + 24 * MB);  // [32][2048][64] 8 MB
    _Float16* Vtg = (_Float16*)(ws + 32 * MB);  // [32][64][2048] 8 MB
    _Float16* AO  = (_Float16*)(ws + 40 * MB);  // [4096][1024]   8 MB

    prep_kernel<<<8192, 256, 0, stream>>>(x, Wqkv, Wproj, Xh, Wqt, Wpt);
    gemm_qkv<<<dim3(24, 32), 256, 0, stream>>>(Xh, Wqt, bqkv, Qg, Kg, Vtg);
    attn_kernel<<<dim3(32, 16), 256, 0, stream>>>(Qg, Kg, Vtg, AO);
    gemm_proj<<<dim3(8, 64), 256, 0, stream>>>(AO, Wpt, bproj, out);
}